// Round 9
// baseline (52.656 us; speedup 1.0000x reference)
//
#include <hip/hip_runtime.h>
#include <hip/hip_bf16.h>
#include <cstdint>
#include <cstddef>

#define NUM_CLASS 32
#define D_DIM 256
#define PIX_PER_IMG 25600          // 160*160
#define TILE_PX 64
#define TILES_PER_IMG 400          // 25600/64
#define N_TILES 3200               // 8 images * 400
#define BLOCK_THREADS 512
#define MAX_GRID 512               // 2 resident blocks/CU

typedef __attribute__((ext_vector_type(4))) float  f32x4;
typedef __attribute__((ext_vector_type(8))) __bf16 bf16x8;
typedef unsigned short ushort8 __attribute__((ext_vector_type(8)));
typedef unsigned short us4v    __attribute__((ext_vector_type(4)));
typedef unsigned int   uint2v  __attribute__((ext_vector_type(2)));

// RNE float -> bf16 bits (finite inputs only) — scalar path
__device__ __forceinline__ unsigned short f2bf(float x) {
    unsigned u = __builtin_bit_cast(unsigned, x);
    unsigned r = (u + 0x7fffu + ((u >> 16) & 1u)) >> 16;
    return (unsigned short)r;
}
__device__ __forceinline__ float bf2f(unsigned short h) {
    return __builtin_bit_cast(float, (unsigned)h << 16);
}

// HW packed f32->bf16 (RNE), 2 values per instruction
__device__ __forceinline__ unsigned cvt_pk_bf16(float lo, float hi) {
    unsigned r;
    asm("v_cvt_pk_bf16_f32 %0, %1, %2" : "=v"(r) : "v"(lo), "v"(hi));
    return r;
}

// bf16 tile addressing: row-major [rows][64] bf16, 128B rows, 8 slots of 16B
// (8 px). Swizzle: slot j -> j ^ (row&7). Write granularity 8B (4 px, p4=0..15).
__device__ __forceinline__ int bt_w(int row, int p4) {
    return row * 128 + ((((p4 >> 1) ^ (row & 7)) << 4)) + ((p4 & 1) << 3);
}
__device__ __forceinline__ int bt_r(int row, int j) {   // 16B slot read
    return row * 128 + (((j ^ (row & 7)) << 4));
}

__global__ __launch_bounds__(BLOCK_THREADS, 4)   // cap VGPR<=128 -> 2 blocks/CU
void emb_main(const float* __restrict__ feat, const float* __restrict__ mask,
              unsigned short* __restrict__ part, float* __restrict__ npart, int G)
{
    __shared__ __align__(16) unsigned char ftb[2][D_DIM * 128];      // 2x32KB bf16 [256][64]
    __shared__ __align__(16) unsigned char mtb[2][NUM_CLASS * 128];  // 2x4KB  bf16 [32][64]
    __shared__ __align__(16) float ssq_s[8][TILE_PX];                // 2KB
    __shared__ __align__(16) unsigned short inv_bf[2][TILE_PX];      // 2x128B

    const int t = threadIdx.x;
    const int lane = t & 63;
    const int wave = t >> 6;           // 0..7
    const int blk  = blockIdx.x;
    const int lh = lane >> 4;          // 0..3
    const int ll = lane & 15;          // 0..15
    const int mc  = t >> 4;            // mask class row 0..31
    const int mpg = t & 15;            // mask pixel group

    const int nt = (blk < N_TILES) ? ((N_TILES - 1 - blk) / G + 1) : 0;

    f32x4 acc[2][2] = {};              // [class-tile][d-tile]
    float nc = 0.f;                    // this thread's class-pixel count (class mc)

    f32x4 fv[8];                       // in-flight feature tile (8 rows x 4 px)
    f32x4 mv;                          // in-flight mask row-chunk

    auto issue = [&](int ti) {
        const int b  = ti / TILES_PER_IMG;
        const int p0 = (ti - b * TILES_PER_IMG) * TILE_PX;
        const float* fb = feat + (size_t)b * ((size_t)D_DIM * PIX_PER_IMG) + p0 + ll * 4;
        #pragma unroll
        for (int k = 0; k < 8; ++k) {
            const int d = wave * 4 + lh + 32 * k;
            fv[k] = *(const f32x4*)(fb + (size_t)d * PIX_PER_IMG);
        }
        mv = *(const f32x4*)(mask + (size_t)b * (NUM_CLASS * PIX_PER_IMG)
                             + (size_t)mc * PIX_PER_IMG + p0 + mpg * 4);
    };

    // A-build: mtb[b] := mask ? inv_bf[b] : 0 (in place, bf16), 4 px per thread
    auto abuild = [&](int b) {
        const int row = t >> 4, p4 = t & 15;
        unsigned char* ap = mtb[b] + bt_w(row, p4);
        const us4v m  = *(const us4v*)ap;
        const us4v iv = *(const us4v*)&inv_bf[b][p4 * 4];
        us4v r;
        #pragma unroll
        for (int q = 0; q < 4; ++q) r[q] = m[q] ? iv[q] : (unsigned short)0;
        *(us4v*)ap = r;
    };

    // MFMA on tile staged in buffer b (A pre-built in mtb[b])
    auto domfma = [&](int b) {
        const unsigned char* fb2 = ftb[b];
        const unsigned char* mb2 = mtb[b];
        const int dbase = wave * 32;
        #pragma unroll
        for (int ks = 0; ks < 2; ++ks) {
            const int j = ks * 4 + lh;             // 16B slot (8 px)
            const ushort8 a0 = *(const ushort8*)(mb2 + bt_r(ll,      j));
            const ushort8 a1 = *(const ushort8*)(mb2 + bt_r(16 + ll, j));
            const ushort8 b0 = *(const ushort8*)(fb2 + bt_r(dbase + ll,      j));
            const ushort8 b1 = *(const ushort8*)(fb2 + bt_r(dbase + 16 + ll, j));
            const bf16x8 ba0 = __builtin_bit_cast(bf16x8, a0);
            const bf16x8 ba1 = __builtin_bit_cast(bf16x8, a1);
            const bf16x8 bb0 = __builtin_bit_cast(bf16x8, b0);
            const bf16x8 bb1 = __builtin_bit_cast(bf16x8, b1);
            acc[0][0] = __builtin_amdgcn_mfma_f32_16x16x32_bf16(ba0, bb0, acc[0][0], 0, 0, 0);
            acc[0][1] = __builtin_amdgcn_mfma_f32_16x16x32_bf16(ba0, bb1, acc[0][1], 0, 0, 0);
            acc[1][0] = __builtin_amdgcn_mfma_f32_16x16x32_bf16(ba1, bb0, acc[1][0], 0, 0, 0);
            acc[1][1] = __builtin_amdgcn_mfma_f32_16x16x32_bf16(ba1, bb1, acc[1][1], 0, 0, 0);
        }
    };

    if (nt > 0) issue(blk);

    for (int i = 0; i < nt; ++i) {
        const int b = i & 1;

        // ---- X(i): stage tile i, ssq, issue i+1, A-build for tile i-1 ----
        f32x4 ss = {0.f, 0.f, 0.f, 0.f};
        #pragma unroll
        for (int k = 0; k < 8; ++k) {
            const int d = wave * 4 + lh + 32 * k;
            ss += fv[k] * fv[k];
            uint2v w;
            w.x = cvt_pk_bf16(fv[k].x, fv[k].y);
            w.y = cvt_pk_bf16(fv[k].z, fv[k].w);
            *(uint2v*)(ftb[b] + bt_w(d, ll)) = w;
        }
        nc += mv.x + mv.y + mv.z + mv.w;
        {
            uint2v w;
            w.x = cvt_pk_bf16(mv.x, mv.y);
            w.y = cvt_pk_bf16(mv.z, mv.w);
            *(uint2v*)(mtb[b] + bt_w(mc, mpg)) = w;
        }
        if (i + 1 < nt) issue(blk + (i + 1) * G);
        if (i > 0) abuild(b ^ 1);
        // reduce ssq across the 4 row-groups (lh) sharing pixel group ll
        ss.x += __shfl_down(ss.x, 32); ss.y += __shfl_down(ss.y, 32);
        ss.z += __shfl_down(ss.z, 32); ss.w += __shfl_down(ss.w, 32);
        ss.x += __shfl_down(ss.x, 16); ss.y += __shfl_down(ss.y, 16);
        ss.z += __shfl_down(ss.z, 16); ss.w += __shfl_down(ss.w, 16);
        if (lane < 16) *(f32x4*)&ssq_s[wave][lane * 4] = ss;

        __builtin_amdgcn_sched_barrier(0);
        asm volatile("s_waitcnt lgkmcnt(0)" ::: "memory");
        __builtin_amdgcn_s_barrier();
        __builtin_amdgcn_sched_barrier(0);

        // ---- Y(i): inv-norm(i) (t<64) overlapped with MFMA(i-1) ----
        if (t < TILE_PX) {
            float tot = 0.f;
            #pragma unroll
            for (int w = 0; w < 8; ++w) tot += ssq_s[w][t];
            inv_bf[b][t] = f2bf(1.0f / fmaxf(sqrtf(tot), 1e-8f));
        }
        if (i > 0) domfma(b ^ 1);

        __builtin_amdgcn_sched_barrier(0);
        asm volatile("s_waitcnt lgkmcnt(0)" ::: "memory");
        __builtin_amdgcn_s_barrier();
        __builtin_amdgcn_sched_barrier(0);
    }

    // ---- tail: A-build + MFMA for tile nt-1 ----
    if (nt > 0) {
        const int b = (nt - 1) & 1;
        abuild(b);
        __builtin_amdgcn_sched_barrier(0);
        asm volatile("s_waitcnt lgkmcnt(0)" ::: "memory");
        __builtin_amdgcn_s_barrier();
        __builtin_amdgcn_sched_barrier(0);
        domfma(b);
    }

    // ---- per-block partial s, bf16 (C/D: col=lane&15, row=(lane>>4)*4+reg) ----
    {
        unsigned short* myout = part + (size_t)blk * (NUM_CLASS * D_DIM);
        const int dbase = wave * 32;
        #pragma unroll
        for (int m = 0; m < 2; ++m)
            #pragma unroll
            for (int n = 0; n < 2; ++n)
                #pragma unroll
                for (int r = 0; r < 4; ++r) {
                    const int c = m * 16 + lh * 4 + r;
                    const int d = dbase + n * 16 + ll;
                    myout[c * D_DIM + d] = f2bf(acc[m][n][r]);
                }
    }
    // n-counts: reduce within each 16-lane class group
    nc += __shfl_down(nc, 8);
    nc += __shfl_down(nc, 4);
    nc += __shfl_down(nc, 2);
    nc += __shfl_down(nc, 1);
    if (mpg == 0) npart[(size_t)blk * NUM_CLASS + mc] = nc;
}

__global__ __launch_bounds__(1024)
void emb_reduce(const unsigned short* __restrict__ part, const float* __restrict__ npart,
                float* __restrict__ cls, int G)
{
    const int c = blockIdx.x;          // class
    const int t = threadIdx.x;
    const int d = t & 255, gs = t >> 8;        // d-slot, g-stripe 0..3
    float s = 0.f;
    #pragma unroll 8
    for (int g = gs; g < G; g += 4)
        s += bf2f(part[(size_t)g * (NUM_CLASS * D_DIM) + c * D_DIM + d]);
    __shared__ float red[4][256];
    red[gs][d] = s;
    float nsum = 0.f;
    for (int g = t; g < G; g += 1024) nsum += npart[(size_t)g * NUM_CLASS + c];
    __syncthreads();
    float s2 = 0.f;
    if (t < 256) {
        const float tot = red[0][t] + red[1][t] + red[2][t] + red[3][t];
        s2 = tot * tot;
    }
    const int lane = t & 63, wave = t >> 6;
    #pragma unroll
    for (int off = 32; off > 0; off >>= 1) {
        s2   += __shfl_down(s2, off);
        nsum += __shfl_down(nsum, off);
    }
    __shared__ float rs[16], rn[16];
    if (lane == 0) { rs[wave] = s2; rn[wave] = nsum; }
    __syncthreads();
    if (t == 0) {
        float S2 = 0.f, N = 0.f;
        #pragma unroll
        for (int w = 0; w < 16; ++w) { S2 += rs[w]; N += rn[w]; }
        const float pair = 0.5f * (S2 - N);
        const float den  = 0.5f * N * (N + 1.0f);
        cls[c] = (N > 0.f) ? (pair / fmaxf(den, 1.0f)) : 0.f;
    }
}

__global__ void emb_final(const float* __restrict__ cls, float* __restrict__ out)
{
    const int t = threadIdx.x;         // 64 threads
    float v = (t < NUM_CLASS) ? cls[t] : 0.f;
    #pragma unroll
    for (int off = 32; off > 0; off >>= 1) v += __shfl_down(v, off);
    if (t == 0) {
        const float emb = v / (float)NUM_CLASS;
        out[0] = 1.0f * expf(-2.0f * emb);     // ALPHA * exp(-GAMMA * emb)
    }
}

extern "C" void kernel_launch(void* const* d_in, const int* in_sizes, int n_in,
                              void* d_out, int out_size, void* d_ws, size_t ws_size,
                              hipStream_t stream)
{
    const float* feat = (const float*)d_in[0];
    const float* mask = (const float*)d_in[1];
    float* out = (float*)d_out;

    // ws: part bf16 [G][32][256] | npart f32 [G][32] | cls[32]
    const size_t per_blk = (size_t)(NUM_CLASS * D_DIM) * sizeof(unsigned short)
                         + (size_t)NUM_CLASS * sizeof(float);
    int G = MAX_GRID;
    size_t need = (size_t)G * per_blk + NUM_CLASS * sizeof(float);
    if (ws_size < need) {
        size_t g = (ws_size > NUM_CLASS * sizeof(float))
                       ? (ws_size - NUM_CLASS * sizeof(float)) / per_blk : 1;
        if (g < 1) g = 1;
        if (g > MAX_GRID) g = MAX_GRID;
        G = (int)g;
    }
    unsigned short* part = (unsigned short*)d_ws;
    float* npart = (float*)(part + (size_t)G * (NUM_CLASS * D_DIM));
    float* cls   = npart + (size_t)G * NUM_CLASS;

    emb_main<<<G, BLOCK_THREADS, 0, stream>>>(feat, mask, part, npart, G);
    emb_reduce<<<NUM_CLASS, 1024, 0, stream>>>(part, npart, cls, G);
    emb_final<<<1, 64, 0, stream>>>(cls, out);
}

// Round 10
// 48.178 us; speedup vs baseline: 1.0930x; 1.0930x over previous
//
#include <hip/hip_runtime.h>
#include <hip/hip_bf16.h>
#include <cstdint>
#include <cstddef>

#define NUM_CLASS 32
#define D_DIM 256
#define PIX_PER_IMG 25600          // 160*160
#define TILE_PX 64
#define TILES_PER_IMG 400          // 25600/64
#define N_TILES 3200               // 8 images * 400
#define BLOCK_THREADS 512
#define MAX_GRID 256

typedef __attribute__((ext_vector_type(4))) float  f32x4;
typedef __attribute__((ext_vector_type(8))) __bf16 bf16x8;
typedef unsigned short ushort8 __attribute__((ext_vector_type(8)));
typedef unsigned short us4v    __attribute__((ext_vector_type(4)));
typedef unsigned int   uint2v  __attribute__((ext_vector_type(2)));

// RNE float -> bf16 bits (finite inputs only) — scalar path
__device__ __forceinline__ unsigned short f2bf(float x) {
    unsigned u = __builtin_bit_cast(unsigned, x);
    unsigned r = (u + 0x7fffu + ((u >> 16) & 1u)) >> 16;
    return (unsigned short)r;
}
__device__ __forceinline__ float bf2f(unsigned short h) {
    return __builtin_bit_cast(float, (unsigned)h << 16);
}

// HW packed f32->bf16 (RNE), 2 values per instruction
__device__ __forceinline__ unsigned cvt_pk_bf16(float lo, float hi) {
    unsigned r;
    asm("v_cvt_pk_bf16_f32 %0, %1, %2" : "=v"(r) : "v"(lo), "v"(hi));
    return r;
}

// bf16 tile addressing: row-major [rows][64] bf16, 128B rows, 8 slots of 16B
// (8 px). Swizzle: slot j -> j ^ (row&7). Write granularity 8B (4 px, p4=0..15).
__device__ __forceinline__ int bt_w(int row, int p4) {
    return row * 128 + ((((p4 >> 1) ^ (row & 7)) << 4)) + ((p4 & 1) << 3);
}
__device__ __forceinline__ int bt_r(int row, int j) {   // 16B slot read
    return row * 128 + (((j ^ (row & 7)) << 4));
}

__global__ __launch_bounds__(BLOCK_THREADS, 4)   // cap VGPR<=128
void emb_main(const float* __restrict__ feat, const float* __restrict__ mask,
              unsigned short* __restrict__ part, float* __restrict__ npart, int G)
{
    __shared__ __align__(16) unsigned char ftb[2][D_DIM * 128];      // 2x32KB bf16 [256][64]
    __shared__ __align__(16) unsigned char mtb[2][NUM_CLASS * 128];  // 2x4KB  bf16 [32][64]
    __shared__ __align__(16) float ssq_s[8][TILE_PX];                // 2KB
    __shared__ __align__(16) unsigned short inv_bf[2][TILE_PX];      // 2x128B

    const int t = threadIdx.x;
    const int lane = t & 63;
    const int wave = t >> 6;           // 0..7
    const int blk  = blockIdx.x;
    const int lh = lane >> 4;          // 0..3
    const int ll = lane & 15;          // 0..15
    const int mc  = t >> 4;            // mask class row 0..31
    const int mpg = t & 15;            // mask pixel group

    const int nt = (blk < N_TILES) ? ((N_TILES - 1 - blk) / G + 1) : 0;

    f32x4 acc[2][2] = {};              // [class-tile][d-tile]
    float nc = 0.f;                    // this thread's class-pixel count (class mc)

    f32x4 fv[8];                       // in-flight feature tile (8 rows x 4 px)
    f32x4 mv;                          // in-flight mask row-chunk

    auto issue = [&](int ti) {
        const int b  = ti / TILES_PER_IMG;
        const int p0 = (ti - b * TILES_PER_IMG) * TILE_PX;
        const float* fb = feat + (size_t)b * ((size_t)D_DIM * PIX_PER_IMG) + p0 + ll * 4;
        #pragma unroll
        for (int k = 0; k < 8; ++k) {
            const int d = wave * 4 + lh + 32 * k;
            fv[k] = *(const f32x4*)(fb + (size_t)d * PIX_PER_IMG);
        }
        mv = *(const f32x4*)(mask + (size_t)b * (NUM_CLASS * PIX_PER_IMG)
                             + (size_t)mc * PIX_PER_IMG + p0 + mpg * 4);
    };

    // A-build: mtb[b] := mask ? inv_bf[b] : 0 (in place, bf16), 4 px per thread
    auto abuild = [&](int b) {
        const int row = t >> 4, p4 = t & 15;
        unsigned char* ap = mtb[b] + bt_w(row, p4);
        const us4v m  = *(const us4v*)ap;
        const us4v iv = *(const us4v*)&inv_bf[b][p4 * 4];
        us4v r;
        #pragma unroll
        for (int q = 0; q < 4; ++q) r[q] = m[q] ? iv[q] : (unsigned short)0;
        *(us4v*)ap = r;
    };

    // MFMA on tile staged in buffer b (A pre-built in mtb[b])
    auto domfma = [&](int b) {
        const unsigned char* fb2 = ftb[b];
        const unsigned char* mb2 = mtb[b];
        const int dbase = wave * 32;
        #pragma unroll
        for (int ks = 0; ks < 2; ++ks) {
            const int j = ks * 4 + lh;             // 16B slot (8 px)
            const ushort8 a0 = *(const ushort8*)(mb2 + bt_r(ll,      j));
            const ushort8 a1 = *(const ushort8*)(mb2 + bt_r(16 + ll, j));
            const ushort8 b0 = *(const ushort8*)(fb2 + bt_r(dbase + ll,      j));
            const ushort8 b1 = *(const ushort8*)(fb2 + bt_r(dbase + 16 + ll, j));
            const bf16x8 ba0 = __builtin_bit_cast(bf16x8, a0);
            const bf16x8 ba1 = __builtin_bit_cast(bf16x8, a1);
            const bf16x8 bb0 = __builtin_bit_cast(bf16x8, b0);
            const bf16x8 bb1 = __builtin_bit_cast(bf16x8, b1);
            acc[0][0] = __builtin_amdgcn_mfma_f32_16x16x32_bf16(ba0, bb0, acc[0][0], 0, 0, 0);
            acc[0][1] = __builtin_amdgcn_mfma_f32_16x16x32_bf16(ba0, bb1, acc[0][1], 0, 0, 0);
            acc[1][0] = __builtin_amdgcn_mfma_f32_16x16x32_bf16(ba1, bb0, acc[1][0], 0, 0, 0);
            acc[1][1] = __builtin_amdgcn_mfma_f32_16x16x32_bf16(ba1, bb1, acc[1][1], 0, 0, 0);
        }
    };

    if (nt > 0) issue(blk);

    for (int i = 0; i < nt; ++i) {
        const int b = i & 1;

        // ---- X(i): stage tile i, ssq, issue i+1, A-build for tile i-1 ----
        f32x4 ss = {0.f, 0.f, 0.f, 0.f};
        #pragma unroll
        for (int k = 0; k < 8; ++k) {
            const int d = wave * 4 + lh + 32 * k;
            ss += fv[k] * fv[k];
            uint2v w;
            w.x = cvt_pk_bf16(fv[k].x, fv[k].y);
            w.y = cvt_pk_bf16(fv[k].z, fv[k].w);
            *(uint2v*)(ftb[b] + bt_w(d, ll)) = w;
        }
        nc += mv.x + mv.y + mv.z + mv.w;
        {
            uint2v w;
            w.x = cvt_pk_bf16(mv.x, mv.y);
            w.y = cvt_pk_bf16(mv.z, mv.w);
            *(uint2v*)(mtb[b] + bt_w(mc, mpg)) = w;
        }
        if (i + 1 < nt) issue(blk + (i + 1) * G);
        if (i > 0) abuild(b ^ 1);
        // reduce ssq across the 4 row-groups (lh) sharing pixel group ll
        ss.x += __shfl_down(ss.x, 32); ss.y += __shfl_down(ss.y, 32);
        ss.z += __shfl_down(ss.z, 32); ss.w += __shfl_down(ss.w, 32);
        ss.x += __shfl_down(ss.x, 16); ss.y += __shfl_down(ss.y, 16);
        ss.z += __shfl_down(ss.z, 16); ss.w += __shfl_down(ss.w, 16);
        if (lane < 16) *(f32x4*)&ssq_s[wave][lane * 4] = ss;

        __builtin_amdgcn_sched_barrier(0);
        asm volatile("s_waitcnt lgkmcnt(0)" ::: "memory");
        __builtin_amdgcn_s_barrier();
        __builtin_amdgcn_sched_barrier(0);

        // ---- Y(i): inv-norm(i) (t<64) overlapped with MFMA(i-1) ----
        if (t < TILE_PX) {
            float tot = 0.f;
            #pragma unroll
            for (int w = 0; w < 8; ++w) tot += ssq_s[w][t];
            inv_bf[b][t] = f2bf(1.0f / fmaxf(sqrtf(tot), 1e-8f));
        }
        if (i > 0) domfma(b ^ 1);

        __builtin_amdgcn_sched_barrier(0);
        asm volatile("s_waitcnt lgkmcnt(0)" ::: "memory");
        __builtin_amdgcn_s_barrier();
        __builtin_amdgcn_sched_barrier(0);
    }

    // ---- tail: A-build + MFMA for tile nt-1 ----
    if (nt > 0) {
        const int b = (nt - 1) & 1;
        abuild(b);
        __builtin_amdgcn_sched_barrier(0);
        asm volatile("s_waitcnt lgkmcnt(0)" ::: "memory");
        __builtin_amdgcn_s_barrier();
        __builtin_amdgcn_sched_barrier(0);
        domfma(b);
    }

    // ---- per-block partial s, bf16 (C/D: col=lane&15, row=(lane>>4)*4+reg) ----
    {
        unsigned short* myout = part + (size_t)blk * (NUM_CLASS * D_DIM);
        const int dbase = wave * 32;
        #pragma unroll
        for (int m = 0; m < 2; ++m)
            #pragma unroll
            for (int n = 0; n < 2; ++n)
                #pragma unroll
                for (int r = 0; r < 4; ++r) {
                    const int c = m * 16 + lh * 4 + r;
                    const int d = dbase + n * 16 + ll;
                    myout[c * D_DIM + d] = f2bf(acc[m][n][r]);
                }
    }
    // n-counts: reduce within each 16-lane class group
    nc += __shfl_down(nc, 8);
    nc += __shfl_down(nc, 4);
    nc += __shfl_down(nc, 2);
    nc += __shfl_down(nc, 1);
    if (mpg == 0) npart[(size_t)blk * NUM_CLASS + mc] = nc;
}

__global__ __launch_bounds__(1024)
void emb_reduce(const unsigned short* __restrict__ part, const float* __restrict__ npart,
                float* __restrict__ cls, int G)
{
    const int c = blockIdx.x;          // class
    const int t = threadIdx.x;
    const int d = t & 255, gs = t >> 8;        // d-slot, g-stripe 0..3
    float s = 0.f;
    #pragma unroll 8
    for (int g = gs; g < G; g += 4)
        s += bf2f(part[(size_t)g * (NUM_CLASS * D_DIM) + c * D_DIM + d]);
    __shared__ float red[4][256];
    red[gs][d] = s;
    float nsum = 0.f;
    for (int g = t; g < G; g += 1024) nsum += npart[(size_t)g * NUM_CLASS + c];
    __syncthreads();
    float s2 = 0.f;
    if (t < 256) {
        const float tot = red[0][t] + red[1][t] + red[2][t] + red[3][t];
        s2 = tot * tot;
    }
    const int lane = t & 63, wave = t >> 6;
    #pragma unroll
    for (int off = 32; off > 0; off >>= 1) {
        s2   += __shfl_down(s2, off);
        nsum += __shfl_down(nsum, off);
    }
    __shared__ float rs[16], rn[16];
    if (lane == 0) { rs[wave] = s2; rn[wave] = nsum; }
    __syncthreads();
    if (t == 0) {
        float S2 = 0.f, N = 0.f;
        #pragma unroll
        for (int w = 0; w < 16; ++w) { S2 += rs[w]; N += rn[w]; }
        const float pair = 0.5f * (S2 - N);
        const float den  = 0.5f * N * (N + 1.0f);
        cls[c] = (N > 0.f) ? (pair / fmaxf(den, 1.0f)) : 0.f;
    }
}

__global__ void emb_final(const float* __restrict__ cls, float* __restrict__ out)
{
    const int t = threadIdx.x;         // 64 threads
    float v = (t < NUM_CLASS) ? cls[t] : 0.f;
    #pragma unroll
    for (int off = 32; off > 0; off >>= 1) v += __shfl_down(v, off);
    if (t == 0) {
        const float emb = v / (float)NUM_CLASS;
        out[0] = 1.0f * expf(-2.0f * emb);     // ALPHA * exp(-GAMMA * emb)
    }
}

extern "C" void kernel_launch(void* const* d_in, const int* in_sizes, int n_in,
                              void* d_out, int out_size, void* d_ws, size_t ws_size,
                              hipStream_t stream)
{
    const float* feat = (const float*)d_in[0];
    const float* mask = (const float*)d_in[1];
    float* out = (float*)d_out;

    // ws: part bf16 [G][32][256] | npart f32 [G][32] | cls[32]
    const size_t per_blk = (size_t)(NUM_CLASS * D_DIM) * sizeof(unsigned short)
                         + (size_t)NUM_CLASS * sizeof(float);
    int G = MAX_GRID;
    size_t need = (size_t)G * per_blk + NUM_CLASS * sizeof(float);
    if (ws_size < need) {
        size_t g = (ws_size > NUM_CLASS * sizeof(float))
                       ? (ws_size - NUM_CLASS * sizeof(float)) / per_blk : 1;
        if (g < 1) g = 1;
        if (g > MAX_GRID) g = MAX_GRID;
        G = (int)g;
    }
    unsigned short* part = (unsigned short*)d_ws;
    float* npart = (float*)(part + (size_t)G * (NUM_CLASS * D_DIM));
    float* cls   = npart + (size_t)G * NUM_CLASS;

    emb_main<<<G, BLOCK_THREADS, 0, stream>>>(feat, mask, part, npart, G);
    emb_reduce<<<NUM_CLASS, 1024, 0, stream>>>(part, npart, cls, G);
    emb_final<<<1, 64, 0, stream>>>(cls, out);
}